// Round 1
// baseline (52.415 us; speedup 1.0000x reference)
//
#include <hip/hip_runtime.h>

// SurveyEmbeddings forward:
//   placeholder = (answer<=1) ? answer*lin_w + lin_b : ans_emb[answer]
//   out = LN(placeholder)*ln_g + ln_b + alpha*year_emb[year[b]] + beta*q_emb[q]
//
// Shapes: year[B], answer[B,Q], ans_emb[VOCAB,16], lin_w[16], lin_b[16],
//         ln_g[16], ln_b[16], year_emb[14,16], q_emb[Q,16], alpha[1], beta[1]
// out[B,Q,16] fp32.
//
// Strategy: 4 lanes per row, 1 float4 per lane. Coalesced 16B/lane loads and
// stores; LN reduce via 2x shfl_xor inside the 4-lane group.

typedef float f32x4 __attribute__((ext_vector_type(4)));

#define LN_EPS 1e-5f

template <bool QPOW2>
__global__ __launch_bounds__(256) void survey_fwd(
    const int* __restrict__ year,
    const int* __restrict__ answer,
    const f32x4* __restrict__ ans_emb,   // [VOCAB][4]
    const f32x4* __restrict__ lin_w,     // [4]
    const f32x4* __restrict__ lin_b,     // [4]
    const f32x4* __restrict__ ln_g,      // [4]
    const f32x4* __restrict__ ln_b,      // [4]
    const f32x4* __restrict__ year_emb,  // [N_YEARS][4]
    const f32x4* __restrict__ q_emb,     // [Q][4]
    const float* __restrict__ alpha,
    const float* __restrict__ beta,
    f32x4* __restrict__ out,             // [B*Q][4]
    int nrows, int Q, int qShift)
{
    const float A  = alpha[0];
    const float Bc = beta[0];

    // sub-lane within a row; constant per thread (strides are multiples of 4)
    const int sub = threadIdx.x & 3;
    const f32x4 w  = lin_w[sub];
    const f32x4 lb = lin_b[sub];
    const f32x4 g  = ln_g[sub];
    const f32x4 bb = ln_b[sub];

    const long long total    = (long long)nrows * 4;
    const long long nthreads = (long long)gridDim.x * blockDim.x;
    long long i = (long long)blockIdx.x * blockDim.x + threadIdx.x;

    for (; i < total; i += nthreads) {
        const int row = (int)(i >> 2);
        const int a   = answer[row];            // 4 lanes broadcast-read same addr

        // categorical branch: gather 16B of the 64B embedding row
        f32x4 v = ans_emb[a * 4 + sub];

        // continuous branch (branchless select, a<=1 is rare)
        const float af = (float)a;
        if (a <= 1) {
            v.x = af * w.x + lb.x;
            v.y = af * w.y + lb.y;
            v.z = af * w.z + lb.z;
            v.w = af * w.w + lb.w;
        }

        // LayerNorm over D=16 across the 4-lane group
        float s = v.x + v.y + v.z + v.w;
        s += __shfl_xor(s, 1);
        s += __shfl_xor(s, 2);
        const float mu = s * 0.0625f;

        const float dx = v.x - mu, dy = v.y - mu, dz = v.z - mu, dw = v.w - mu;
        float ss = dx * dx + dy * dy + dz * dz + dw * dw;
        ss += __shfl_xor(ss, 1);
        ss += __shfl_xor(ss, 2);
        const float r = rsqrtf(ss * 0.0625f + LN_EPS);

        const int b = QPOW2 ? (row >> qShift) : (row / Q);
        const int q = QPOW2 ? (row & (Q - 1)) : (row - b * Q);

        const int   yr = year[b];
        const f32x4 ye = year_emb[yr * 4 + sub];
        const f32x4 qe = q_emb[q * 4 + sub];

        f32x4 o;
        o.x = dx * r * g.x + bb.x + A * ye.x + Bc * qe.x;
        o.y = dy * r * g.y + bb.y + A * ye.y + Bc * qe.y;
        o.z = dz * r * g.z + bb.z + A * ye.z + Bc * qe.z;
        o.w = dw * r * g.w + bb.w + A * ye.w + Bc * qe.w;

        __builtin_nontemporal_store(o, &out[i]);  // streaming 256MiB, keep L2 for tables
    }
}

extern "C" void kernel_launch(void* const* d_in, const int* in_sizes, int n_in,
                              void* d_out, int out_size, void* d_ws, size_t ws_size,
                              hipStream_t stream) {
    const int*   year     = (const int*)d_in[0];
    const int*   answer   = (const int*)d_in[1];
    const f32x4* ans_emb  = (const f32x4*)d_in[2];
    const f32x4* lin_w    = (const f32x4*)d_in[3];
    const f32x4* lin_b    = (const f32x4*)d_in[4];
    const f32x4* ln_g     = (const f32x4*)d_in[5];
    const f32x4* ln_b     = (const f32x4*)d_in[6];
    const f32x4* year_emb = (const f32x4*)d_in[7];
    const f32x4* q_emb    = (const f32x4*)d_in[8];
    const float* alpha    = (const float*)d_in[9];
    const float* beta     = (const float*)d_in[10];
    float*       out      = (float*)d_out;

    const int B     = in_sizes[0];
    const int nrows = in_sizes[1];       // B*Q
    const int Q     = nrows / B;

    const long long total_threads = (long long)nrows * 4;
    int blocks = (int)((total_threads + 255) / 256);
    if (blocks > 8192) blocks = 8192;    // grid-stride the rest

    const bool pow2 = (Q & (Q - 1)) == 0;
    int qShift = 0;
    while ((1 << qShift) < Q) ++qShift;

    if (pow2) {
        survey_fwd<true><<<blocks, 256, 0, stream>>>(
            year, answer, ans_emb, lin_w, lin_b, ln_g, ln_b, year_emb, q_emb,
            alpha, beta, (f32x4*)out, nrows, Q, qShift);
    } else {
        survey_fwd<false><<<blocks, 256, 0, stream>>>(
            year, answer, ans_emb, lin_w, lin_b, ln_g, ln_b, year_emb, q_emb,
            alpha, beta, (f32x4*)out, nrows, Q, qShift);
    }
}